// Round 4
// baseline (1781.891 us; speedup 1.0000x reference)
//
#include <hip/hip_runtime.h>

// Implicit-GEMM conv3x3(64->256, VALID) + bias + tanh-GELU + spatial mean.
// v6: v5 (2 output rows per block, 4-row LDS tile) with the row loop forced
// to #pragma unroll 1. v5's unrolled row loop let the scheduler interleave
// both rows -> 128 live acc f32 at the 128-reg cap -> 438B/thread scratch
// spill (WRITE_SIZE 96MB -> 884MB, 464 -> 620us). Runtime r0 guarantees the
// accumulator dies between rows; row-dependent LDS term hoisted to a base
// pointer, inner offsets stay compile-time.
// Inner loop / epilogue identical to the proven v3 (16x16x32, flat tap loop,
// compiler-scheduled; v4's manual pipeline + 32x32 regressed, do not redo).

typedef __attribute__((ext_vector_type(8))) short short8;
typedef __attribute__((ext_vector_type(4))) float floatx4;
typedef __attribute__((ext_vector_type(4))) unsigned int uintx4;
typedef __attribute__((ext_vector_type(2))) unsigned int uintx2;

#define HO 126
#define HB 63    // 2 output rows per block
#define CIP 72   // 64 ci + 8 pad shorts: 144B col stride (16B-aligned b128)

__device__ __forceinline__ unsigned int f2bf(float f) {
    unsigned int u = __float_as_uint(f);
    return (u + 0x7FFFu + ((u >> 16) & 1u)) >> 16;   // RNE
}

__device__ __forceinline__ float gelu_t(float y) {
    float p = __builtin_fmaf(0.044715f, y * y, 1.0f);
    float z2 = -2.3022084f * y * p;
    float e = exp2f(z2);
    return y * __builtin_amdgcn_rcpf(1.0f + e);
}

__global__ __launch_bounds__(256)
void prep_kernel(const float* __restrict__ wgt, float* __restrict__ out,
                 unsigned short* __restrict__ wb2) {
    int g = blockIdx.x * 256 + threadIdx.x;
    if (g < 64 * 256) out[g] = 0.f;               // zero the atomic target
    if (g < 147456) {                             // 9 taps * 2 halves * 16 cog * 64 lane * 8
        int j    = g & 7;
        int lane = (g >> 3) & 63;
        int fc   = g >> 9;                        // 0..287
        int cog  = fc & 15;
        int half = (fc >> 4) & 1;
        int tap  = fc >> 5;
        int li = lane & 15, quad = lane >> 4;
        int co = cog * 16 + li;
        int ci = half * 32 + quad * 8 + j;
        wb2[g] = (unsigned short)f2bf(wgt[(co * 64 + ci) * 9 + tap]);
    }
}

__global__ __launch_bounds__(512, 4)
void conv_kernel(const float* __restrict__ x, const float* __restrict__ bias,
                 const unsigned short* __restrict__ wb2, float* __restrict__ out) {
    __shared__ unsigned short xs[4][130][CIP];    // 74880 B -> 2 blocks/CU

    const int bx = blockIdx.x;
    const int n  = bx / HB;
    const int h0 = (bx % HB) * 2;                 // first of two output rows
    const int tid  = threadIdx.x;
    const int lane = tid & 63;
    const int wave = tid >> 6;
    const int li   = lane & 15;
    const int quad = lane >> 4;
    const int sc = wave & 3;          // co split: coBase = sc*64
    const int sp = wave >> 2;         // pix split: pixBase = sp*64
    const int coBase  = sc * 64;
    const int pixBase = sp * 64;

    // ---- stage x[n][0..63][h0..h0+3][0..127] -> xs[r][col][ci] bf16 (once) ----
    {
        const int col = tid & 127;
        const int g   = tid >> 7;                 // 0..3, each handles 16 of 64 cells
        const float* xg = x + (size_t)n * 64 * 16384 + h0 * 128 + col;
#pragma unroll
        for (int i = 0; i < 16; ++i) {
            int idx = g * 16 + i;                 // cell = r*16 + cq
            int r  = idx >> 4;                    // input row 0..3
            int cq = idx & 15;                    // ci group of 4
            float v0 = xg[(size_t)(cq * 4 + 0) * 16384 + r * 128];
            float v1 = xg[(size_t)(cq * 4 + 1) * 16384 + r * 128];
            float v2 = xg[(size_t)(cq * 4 + 2) * 16384 + r * 128];
            float v3 = xg[(size_t)(cq * 4 + 3) * 16384 + r * 128];
            uintx2 pk;
            pk.x = f2bf(v0) | (f2bf(v1) << 16);
            pk.y = f2bf(v2) | (f2bf(v3) << 16);
            *reinterpret_cast<uintx2*>(&xs[r][col][cq * 4]) = pk;   // ds_write_b64
        }
    }

    __syncthreads();                              // the ONLY barrier

    union Frag { uintx4 u; short8 s; };
    // Runtime-invariant bases; all inner-loop offsets are compile-time.
    const unsigned short* xbase = &xs[0][pixBase + li][0] + quad * 8;
    const unsigned short* abase = wb2 + (size_t)(sc * 4) * 512 + lane * 8;

    const float inv = 1.0f / (126.f * 126.f);

#pragma unroll 1
    for (int r0 = 0; r0 < 2; ++r0) {              // two output rows, STRICTLY serial
        const unsigned short* xrow = xbase + r0 * (130 * CIP);

        floatx4 acc[16];                          // [cf 0..3][pf 0..3]
#pragma unroll
        for (int i = 0; i < 16; ++i) acc[i] = (floatx4){0.f, 0.f, 0.f, 0.f};

#pragma unroll
        for (int tap = 0; tap < 9; ++tap) {
            const int kh = tap / 3;
            const int kw = tap % 3;
            Frag a[8];                            // [half][cf]
#pragma unroll
            for (int hf = 0; hf < 2; ++hf)
#pragma unroll
                for (int cf = 0; cf < 4; ++cf)
                    a[hf * 4 + cf].u = *reinterpret_cast<const uintx4*>(
                        abase + (size_t)(((tap * 2 + hf) * 16) + cf) * 512);
#pragma unroll
            for (int hf = 0; hf < 2; ++hf)
#pragma unroll
                for (int pf = 0; pf < 4; ++pf) {
                    Frag b;
                    b.u = *reinterpret_cast<const uintx4*>(
                        xrow + ((kh * 130 + kw + pf * 16)) * CIP + hf * 32);
#pragma unroll
                    for (int cf = 0; cf < 4; ++cf)
                        acc[cf * 4 + pf] = __builtin_amdgcn_mfma_f32_16x16x32_bf16(
                            a[hf * 4 + cf].s, b.s, acc[cf * 4 + pf], 0, 0, 0);
                }
        }

        // ---- epilogue: bias + GELU + masked pixel sum + reduce + atomic mean ----
#pragma unroll
        for (int cf = 0; cf < 4; ++cf) {
            const floatx4 bv = *reinterpret_cast<const floatx4*>(
                bias + coBase + cf * 16 + quad * 4);
            floatx4 s = (floatx4){0.f, 0.f, 0.f, 0.f};
#pragma unroll
            for (int pf = 0; pf < 4; ++pf) {
                bool valid = (pixBase + pf * 16 + li) < 126;
#pragma unroll
                for (int r = 0; r < 4; ++r) {
                    float gv = gelu_t(acc[cf * 4 + pf][r] + bv[r]);
                    s[r] += valid ? gv : 0.f;     // select: contains poison-col garbage
                }
            }
#pragma unroll
            for (int r = 0; r < 4; ++r) {
                float v = s[r];
                v += __shfl_xor(v, 1);
                v += __shfl_xor(v, 2);
                v += __shfl_xor(v, 4);
                v += __shfl_xor(v, 8);
                if (li == 0)
                    atomicAdd(&out[n * 256 + coBase + cf * 16 + quad * 4 + r], v * inv);
            }
        }
    }
}

extern "C" void kernel_launch(void* const* d_in, const int* in_sizes, int n_in,
                              void* d_out, int out_size, void* d_ws, size_t ws_size,
                              hipStream_t stream) {
    const float* x    = (const float*)d_in[0];
    const float* wgt  = (const float*)d_in[1];
    const float* bias = (const float*)d_in[2];
    float* out = (float*)d_out;
    unsigned short* wb2 = (unsigned short*)d_ws;  // 294912 B, fragment-linear bf16

    prep_kernel<<<576, 256, 0, stream>>>(wgt, out, wb2);
    conv_kernel<<<64 * HB, 512, 0, stream>>>(x, bias, wb2, out);
}

// Round 5
// 694.489 us; speedup vs baseline: 2.5658x; 2.5658x over previous
//
#include <hip/hip_runtime.h>

// Implicit-GEMM conv3x3(64->256, VALID) + bias + tanh-GELU + spatial mean.
// v7 = exact v3 structure (harness-proven 464us conv: 16x16x32 MFMA, flat
// tap loop, compiler-scheduled, 64 VGPR + 64 AGPR, no spill) plus two
// additive, regalloc-neutral levers:
//   (a) XCD-contiguous block swizzle (8064%8==0 -> simple bijective form):
//       adjacent-h blocks share 2/3 staged x rows; co-locating them per XCD
//       turns those HBM re-fetches (FETCH=1.5x input) into L2 hits, cutting
//       exposed pre-barrier staging latency.
//   (b) s_setprio(1) around each 4-MFMA cluster (T5): two resident blocks
//       per CU are phase-offset (no in-loop barriers), so MFMA-phase waves
//       win issue arbitration over staging/epilogue-phase waves.
// HISTORY (do not redo): v4 32x32+manual pipeline -> 695us (scheduler
// freedom loss); v5 2-row unrolled -> 620us (acc spill, 884MB WRITE);
// v6 2-row unroll-1 -> 1568us (acc allocated to scratch, 2.4GB WRITE).
// The 128-reg cap makes acc-topology changes spill; only additive edits.

typedef __attribute__((ext_vector_type(8))) short short8;
typedef __attribute__((ext_vector_type(4))) float floatx4;
typedef __attribute__((ext_vector_type(4))) unsigned int uintx4;
typedef __attribute__((ext_vector_type(2))) unsigned int uintx2;

#define HO 126
#define CIP 72   // 64 ci + 8 pad shorts: 144B col stride (16B-aligned b128)

__device__ __forceinline__ unsigned int f2bf(float f) {
    unsigned int u = __float_as_uint(f);
    return (u + 0x7FFFu + ((u >> 16) & 1u)) >> 16;   // RNE
}

__device__ __forceinline__ float gelu_t(float y) {
    float p = __builtin_fmaf(0.044715f, y * y, 1.0f);
    float z2 = -2.3022084f * y * p;
    float e = exp2f(z2);
    return y * __builtin_amdgcn_rcpf(1.0f + e);
}

__global__ __launch_bounds__(256)
void prep_kernel(const float* __restrict__ wgt, float* __restrict__ out,
                 unsigned short* __restrict__ wb2) {
    int g = blockIdx.x * 256 + threadIdx.x;
    if (g < 64 * 256) out[g] = 0.f;               // zero the atomic target
    if (g < 147456) {                             // 9 taps * 2 halves * 16 cog * 64 lane * 8
        int j    = g & 7;
        int lane = (g >> 3) & 63;
        int fc   = g >> 9;                        // 0..287
        int cog  = fc & 15;
        int half = (fc >> 4) & 1;
        int tap  = fc >> 5;
        int li = lane & 15, quad = lane >> 4;
        int co = cog * 16 + li;
        int ci = half * 32 + quad * 8 + j;
        wb2[g] = (unsigned short)f2bf(wgt[(co * 64 + ci) * 9 + tap]);
    }
}

__global__ __launch_bounds__(512, 4)
void conv_kernel(const float* __restrict__ x, const float* __restrict__ bias,
                 const unsigned short* __restrict__ wb2, float* __restrict__ out) {
    __shared__ unsigned short xs[3][130][CIP];    // 56160 B -> 2 blocks/CU

    // XCD-contiguous bijective swizzle: 8064 blocks, 8 XCDs, 1008 per chunk.
    const int bx0 = blockIdx.x;
    const int bx  = (bx0 & 7) * 1008 + (bx0 >> 3);
    const int n = bx / HO;
    const int h = bx % HO;
    const int tid  = threadIdx.x;
    const int lane = tid & 63;
    const int wave = tid >> 6;
    const int li   = lane & 15;
    const int quad = lane >> 4;
    const int sc = wave & 3;          // co split: coBase = sc*64
    const int sp = wave >> 2;         // pix split: pixBase = sp*64
    const int coBase  = sc * 64;
    const int pixBase = sp * 64;

    // ---- stage x[n][0..63][h..h+2][0..127] -> xs[r][col][ci] bf16 (once) ----
    {
        const int col = tid & 127;
        const int g   = tid >> 7;                 // 0..3, each handles 12 of 48 cells
        const float* xg = x + (size_t)n * 64 * 16384 + h * 128 + col;
#pragma unroll
        for (int i = 0; i < 12; ++i) {
            int idx = g * 12 + i;                 // cell = r*16 + cq
            int r  = idx >> 4;
            int cq = idx & 15;                    // ci group of 4
            float v0 = xg[(size_t)(cq * 4 + 0) * 16384 + r * 128];
            float v1 = xg[(size_t)(cq * 4 + 1) * 16384 + r * 128];
            float v2 = xg[(size_t)(cq * 4 + 2) * 16384 + r * 128];
            float v3 = xg[(size_t)(cq * 4 + 3) * 16384 + r * 128];
            uintx2 pk;
            pk.x = f2bf(v0) | (f2bf(v1) << 16);
            pk.y = f2bf(v2) | (f2bf(v3) << 16);
            *reinterpret_cast<uintx2*>(&xs[r][col][cq * 4]) = pk;   // ds_write_b64
        }
    }

    floatx4 acc[16];                              // [cf 0..3][pf 0..3]
#pragma unroll
    for (int i = 0; i < 16; ++i) acc[i] = (floatx4){0.f, 0.f, 0.f, 0.f};

    __syncthreads();                              // the ONLY barrier

    union Frag { uintx4 u; short8 s; };
    // Runtime-invariant bases; all loop offsets are compile-time constants.
    const unsigned short* xbase = &xs[0][pixBase + li][0] + quad * 8;
    const unsigned short* abase = wb2 + (size_t)(sc * 4) * 512 + lane * 8;

#pragma unroll
    for (int tap = 0; tap < 9; ++tap) {
        const int kh = tap / 3;
        const int kw = tap % 3;
        Frag a[8];                                // [half][cf]
#pragma unroll
        for (int hf = 0; hf < 2; ++hf)
#pragma unroll
            for (int cf = 0; cf < 4; ++cf)
                a[hf * 4 + cf].u = *reinterpret_cast<const uintx4*>(
                    abase + (size_t)(((tap * 2 + hf) * 16) + cf) * 512);
#pragma unroll
        for (int hf = 0; hf < 2; ++hf)
#pragma unroll
            for (int pf = 0; pf < 4; ++pf) {
                Frag b;
                b.u = *reinterpret_cast<const uintx4*>(
                    xbase + (kh * 130 + kw + pf * 16) * CIP + hf * 32);  // ds_read_b128
                __builtin_amdgcn_s_setprio(1);    // T5: favor MFMA-phase waves
#pragma unroll
                for (int cf = 0; cf < 4; ++cf)
                    acc[cf * 4 + pf] = __builtin_amdgcn_mfma_f32_16x16x32_bf16(
                        a[hf * 4 + cf].s, b.s, acc[cf * 4 + pf], 0, 0, 0);
                __builtin_amdgcn_s_setprio(0);
            }
    }

    // ---- epilogue: bias + GELU + masked pixel sum + reduce + atomic mean ----
    const float inv = 1.0f / (126.f * 126.f);
#pragma unroll
    for (int cf = 0; cf < 4; ++cf) {
        const floatx4 bv = *reinterpret_cast<const floatx4*>(
            bias + coBase + cf * 16 + quad * 4);
        floatx4 s = (floatx4){0.f, 0.f, 0.f, 0.f};
#pragma unroll
        for (int pf = 0; pf < 4; ++pf) {
            bool valid = (pixBase + pf * 16 + li) < 126;
#pragma unroll
            for (int r = 0; r < 4; ++r) {
                float gv = gelu_t(acc[cf * 4 + pf][r] + bv[r]);
                s[r] += valid ? gv : 0.f;         // select: contains poison-col NaNs
            }
        }
#pragma unroll
        for (int r = 0; r < 4; ++r) {
            float v = s[r];
            v += __shfl_xor(v, 1);
            v += __shfl_xor(v, 2);
            v += __shfl_xor(v, 4);
            v += __shfl_xor(v, 8);
            if (li == 0)
                atomicAdd(&out[n * 256 + coBase + cf * 16 + quad * 4 + r], v * inv);
        }
    }
}

extern "C" void kernel_launch(void* const* d_in, const int* in_sizes, int n_in,
                              void* d_out, int out_size, void* d_ws, size_t ws_size,
                              hipStream_t stream) {
    const float* x    = (const float*)d_in[0];
    const float* wgt  = (const float*)d_in[1];
    const float* bias = (const float*)d_in[2];
    float* out = (float*)d_out;
    unsigned short* wb2 = (unsigned short*)d_ws;  // 294912 B, fragment-linear bf16

    prep_kernel<<<576, 256, 0, stream>>>(wgt, out, wb2);
    conv_kernel<<<64 * HO, 512, 0, stream>>>(x, bias, wb2, out);
}